// Round 1
// baseline (1874.321 us; speedup 1.0000x reference)
//
#include <hip/hip_runtime.h>

#define NN 50000      // nodes
#define DIM 64        // feature dim
#define NHEAD 4
#define NEDGE 800000
#define NLAYER 3
#define LN_EPS 1e-5f

__device__ __forceinline__ float waveReduceSum(float x) {
    x += __shfl_xor(x, 32, 64);
    x += __shfl_xor(x, 16, 64);
    x += __shfl_xor(x, 8, 64);
    x += __shfl_xor(x, 4, 64);
    x += __shfl_xor(x, 2, 64);
    x += __shfl_xor(x, 1, 64);
    return x;
}

__device__ __forceinline__ void atomicMaxFloat(float* addr, float val) {
    if (val >= 0.f) {
        atomicMax((int*)addr, __float_as_int(val));
    } else {
        atomicMin((unsigned int*)addr, __float_as_uint(val));
    }
}

// init smax=-inf, denom=0, agg=0
__global__ __launch_bounds__(256) void init_kernel(float* __restrict__ smax,
                                                   float* __restrict__ denom,
                                                   float* __restrict__ agg) {
    int i = blockIdx.x * blockDim.x + threadIdx.x;
    if (i < NN * DIM) agg[i] = 0.f;
    if (i < NN * NHEAD) {
        smax[i] = __int_as_float(0xff800000u);  // -inf
        denom[i] = 0.f;
    }
}

// q,k,v = feats @ W{q,k,v} + b ; wave per row, lane j owns output col j
__global__ __launch_bounds__(256) void qkv_kernel(
    const float* __restrict__ feats,
    const float* __restrict__ Wq, const float* __restrict__ Wk, const float* __restrict__ Wv,
    const float* __restrict__ bq, const float* __restrict__ bk, const float* __restrict__ bv,
    float* __restrict__ q, float* __restrict__ k, float* __restrict__ v) {
    int wave = threadIdx.x >> 6;
    int lane = threadIdx.x & 63;
    int n = blockIdx.x * 4 + wave;
    if (n >= NN) return;
    float f = feats[n * DIM + lane];
    float aq = bq[lane], ak = bk[lane], av = bv[lane];
    #pragma unroll
    for (int kk = 0; kk < DIM; ++kk) {
        float fk = __shfl(f, kk, 64);
        aq = fmaf(fk, Wq[kk * DIM + lane], aq);
        ak = fmaf(fk, Wk[kk * DIM + lane], ak);
        av = fmaf(fk, Wv[kk * DIM + lane], av);
    }
    q[n * DIM + lane] = aq;
    k[n * DIM + lane] = ak;
    v[n * DIM + lane] = av;
}

// scores[e,h] = dot(q[dst,h], k[src,h]) * 0.25 * attr[e];  atomicMax into smax[dst,h]
__global__ __launch_bounds__(256) void scores_kernel(
    const int* __restrict__ ei, const float* __restrict__ attr,
    const float* __restrict__ q, const float* __restrict__ k,
    float* __restrict__ scores, float* __restrict__ smax) {
    int wave = threadIdx.x >> 6;
    int lane = threadIdx.x & 63;
    int e = blockIdx.x * 4 + wave;
    if (e >= NEDGE) return;
    int src = ei[e];
    int dst = ei[NEDGE + e];
    float p = q[dst * DIM + lane] * k[src * DIM + lane];
    // reduce within 16-lane head groups
    p += __shfl_xor(p, 1, 64);
    p += __shfl_xor(p, 2, 64);
    p += __shfl_xor(p, 4, 64);
    p += __shfl_xor(p, 8, 64);
    if ((lane & 15) == 0) {
        int h = lane >> 4;
        float s = p * 0.25f * attr[e];
        scores[e * NHEAD + h] = s;
        atomicMaxFloat(&smax[dst * NHEAD + h], s);
    }
}

// w = exp(score - smax[dst]); denom[dst,h] += w; agg[dst,:] += w * v[src,:]
__global__ __launch_bounds__(256) void agg_kernel(
    const int* __restrict__ ei,
    const float* __restrict__ scores, const float* __restrict__ smax,
    const float* __restrict__ v,
    float* __restrict__ denom, float* __restrict__ agg) {
    int wave = threadIdx.x >> 6;
    int lane = threadIdx.x & 63;
    int e = blockIdx.x * 4 + wave;
    if (e >= NEDGE) return;
    int src = ei[e];
    int dst = ei[NEDGE + e];
    int h = lane >> 4;
    float w = __expf(scores[e * NHEAD + h] - smax[dst * NHEAD + h]);
    if (lane < NHEAD) {
        float wl = __expf(scores[e * NHEAD + lane] - smax[dst * NHEAD + lane]);
        atomicAdd(&denom[dst * NHEAD + lane], wl);
    }
    float vv = v[src * DIM + lane];
    atomicAdd(&agg[dst * DIM + lane], w * vv);
}

// fused: att = (agg/denom)@Wo+bo ; x=feats+att ; LN1 ; h=relu(x@W1+b1) ;
//        y=h@W2+b2 ; x2=x+y ; LN2 -> out
__global__ __launch_bounds__(256) void post_kernel(
    const float* __restrict__ feats_in,
    const float* __restrict__ agg, const float* __restrict__ denom,
    const float* __restrict__ Wo, const float* __restrict__ bo,
    const float* __restrict__ W1, const float* __restrict__ b1,
    const float* __restrict__ W2, const float* __restrict__ b2,
    const float* __restrict__ g1, const float* __restrict__ be1,
    const float* __restrict__ g2, const float* __restrict__ be2,
    float* __restrict__ out) {
    int wave = threadIdx.x >> 6;
    int lane = threadIdx.x & 63;
    int n = blockIdx.x * 4 + wave;
    if (n >= NN) return;

    float d = denom[n * NHEAD + (lane >> 4)];
    float a = agg[n * DIM + lane];
    a = (d > 0.f) ? a / d : 0.f;

    float att = bo[lane];
    #pragma unroll
    for (int kk = 0; kk < DIM; ++kk) {
        float ak = __shfl(a, kk, 64);
        att = fmaf(ak, Wo[kk * DIM + lane], att);
    }
    float x = feats_in[n * DIM + lane] + att;

    float mean = waveReduceSum(x) * (1.f / 64.f);
    float xc = x - mean;
    float var = waveReduceSum(xc * xc) * (1.f / 64.f);
    float fm = xc * rsqrtf(var + LN_EPS) * g1[lane] + be1[lane];

    float h = b1[lane];
    #pragma unroll
    for (int kk = 0; kk < DIM; ++kk) {
        float fk = __shfl(fm, kk, 64);
        h = fmaf(fk, W1[kk * DIM + lane], h);
    }
    h = fmaxf(h, 0.f);

    float y = b2[lane];
    #pragma unroll
    for (int kk = 0; kk < DIM; ++kk) {
        float hk = __shfl(h, kk, 64);
        y = fmaf(hk, W2[kk * DIM + lane], y);
    }
    float x2 = fm + y;

    float mean2 = waveReduceSum(x2) * (1.f / 64.f);
    float xc2 = x2 - mean2;
    float var2 = waveReduceSum(xc2 * xc2) * (1.f / 64.f);
    out[n * DIM + lane] = xc2 * rsqrtf(var2 + LN_EPS) * g2[lane] + be2[lane];
}

extern "C" void kernel_launch(void* const* d_in, const int* in_sizes, int n_in,
                              void* d_out, int out_size, void* d_ws, size_t ws_size,
                              hipStream_t stream) {
    const float* feats = (const float*)d_in[0];
    const int*   ei    = (const int*)d_in[1];
    const float* attr  = (const float*)d_in[2];
    const float* Wq = (const float*)d_in[3];
    const float* Wk = (const float*)d_in[4];
    const float* Wv = (const float*)d_in[5];
    const float* Wo = (const float*)d_in[6];
    const float* W1 = (const float*)d_in[7];
    const float* W2 = (const float*)d_in[8];
    const float* bq = (const float*)d_in[9];
    const float* bk = (const float*)d_in[10];
    const float* bv = (const float*)d_in[11];
    const float* bo = (const float*)d_in[12];
    const float* b1 = (const float*)d_in[13];
    const float* b2 = (const float*)d_in[14];
    const float* g1  = (const float*)d_in[15];
    const float* be1 = (const float*)d_in[16];
    const float* g2  = (const float*)d_in[17];
    const float* be2 = (const float*)d_in[18];

    float* out = (float*)d_out;
    float* ws = (float*)d_ws;

    const size_t ND = (size_t)NN * DIM;
    float* q      = ws;
    float* k      = ws + ND;
    float* v      = ws + 2 * ND;
    float* agg    = ws + 3 * ND;
    float* scores = ws + 4 * ND;                       // E * NHEAD
    float* smax   = scores + (size_t)NEDGE * NHEAD;    // NN * NHEAD
    float* denom  = smax + (size_t)NN * NHEAD;         // NN * NHEAD

    const float* fin = feats;
    for (int l = 0; l < NLAYER; ++l) {
        const size_t wOff = (size_t)l * DIM * DIM;
        const size_t bOff = (size_t)l * DIM;

        init_kernel<<<(NN * DIM + 255) / 256, 256, 0, stream>>>(smax, denom, agg);

        qkv_kernel<<<NN / 4, 256, 0, stream>>>(
            fin, Wq + wOff, Wk + wOff, Wv + wOff,
            bq + bOff, bk + bOff, bv + bOff, q, k, v);

        scores_kernel<<<NEDGE / 4, 256, 0, stream>>>(ei, attr, q, k, scores, smax);

        agg_kernel<<<NEDGE / 4, 256, 0, stream>>>(ei, scores, smax, v, denom, agg);

        post_kernel<<<NN / 4, 256, 0, stream>>>(
            fin, agg, denom,
            Wo + wOff, bo + bOff, W1 + wOff, b1 + bOff, W2 + wOff, b2 + bOff,
            g1 + bOff, be1 + bOff, g2 + bOff, be2 + bOff,
            out + (size_t)l * ND);

        fin = out + (size_t)l * ND;
    }
}

// Round 2
// 1040.715 us; speedup vs baseline: 1.8010x; 1.8010x over previous
//
#include <hip/hip_runtime.h>

#define NN 50000      // nodes
#define DIM 64        // feature dim
#define NHEAD 4
#define NEDGE 800000
#define NLAYER 3
#define LN_EPS 1e-5f
#define SCAN_BLOCKS ((NN + 255) / 256)   // 196

__device__ __forceinline__ float waveReduceSum(float x) {
    x += __shfl_xor(x, 32, 64);
    x += __shfl_xor(x, 16, 64);
    x += __shfl_xor(x, 8, 64);
    x += __shfl_xor(x, 4, 64);
    x += __shfl_xor(x, 2, 64);
    x += __shfl_xor(x, 1, 64);
    return x;
}

// ---------------- CSR build (once; graph identical across layers) ----------

__global__ __launch_bounds__(256) void zero_kernel(int* __restrict__ p, int n) {
    int i = blockIdx.x * blockDim.x + threadIdx.x;
    if (i < n) p[i] = 0;
}

__global__ __launch_bounds__(256) void deg_kernel(const int* __restrict__ ei,
                                                  int* __restrict__ deg) {
    int e = blockIdx.x * blockDim.x + threadIdx.x;
    if (e < NEDGE) atomicAdd(&deg[ei[NEDGE + e]], 1);
}

// per-block exclusive scan of deg -> tmp, block sums -> bsum
__global__ __launch_bounds__(256) void scan1_kernel(const int* __restrict__ deg,
                                                    int* __restrict__ tmp,
                                                    int* __restrict__ bsum) {
    __shared__ int s[256];
    int t = threadIdx.x;
    int i = blockIdx.x * 256 + t;
    int v = (i < NN) ? deg[i] : 0;
    s[t] = v;
    __syncthreads();
    for (int off = 1; off < 256; off <<= 1) {
        int x = (t >= off) ? s[t - off] : 0;
        __syncthreads();
        s[t] += x;
        __syncthreads();
    }
    if (i < NN) tmp[i] = s[t] - v;           // exclusive
    if (t == 255) bsum[blockIdx.x] = s[255]; // inclusive block total
}

// single-block exclusive scan of block sums (SCAN_BLOCKS <= 256)
__global__ __launch_bounds__(256) void scan2_kernel(int* __restrict__ bsum) {
    __shared__ int s[256];
    int t = threadIdx.x;
    int v = (t < SCAN_BLOCKS) ? bsum[t] : 0;
    s[t] = v;
    __syncthreads();
    for (int off = 1; off < 256; off <<= 1) {
        int x = (t >= off) ? s[t - off] : 0;
        __syncthreads();
        s[t] += x;
        __syncthreads();
    }
    if (t < SCAN_BLOCKS) bsum[t] = s[t] - v; // exclusive
}

__global__ __launch_bounds__(256) void scan3_kernel(const int* __restrict__ tmp,
                                                    const int* __restrict__ bsum,
                                                    int* __restrict__ rowptr) {
    int i = blockIdx.x * 256 + threadIdx.x;
    if (i < NN) rowptr[i] = tmp[i] + bsum[i >> 8];
    if (i == 0) rowptr[NN] = NEDGE;
}

__global__ __launch_bounds__(256) void fill_kernel(const int* __restrict__ ei,
                                                   const float* __restrict__ attr,
                                                   const int* __restrict__ rowptr,
                                                   int* __restrict__ cursor,
                                                   int* __restrict__ csr_src,
                                                   float* __restrict__ csr_attr) {
    int e = blockIdx.x * blockDim.x + threadIdx.x;
    if (e >= NEDGE) return;
    int src = ei[e];
    int dst = ei[NEDGE + e];
    int pos = atomicAdd(&cursor[dst], 1);
    int idx = rowptr[dst] + pos;
    csr_src[idx] = src;
    csr_attr[idx] = attr[e];
}

// ---------------- per-layer kernels ----------------------------------------

// q,k,v = feats @ W{q,k,v} + b ; wave per row, lane j owns output col j
__global__ __launch_bounds__(256) void qkv_kernel(
    const float* __restrict__ feats,
    const float* __restrict__ Wq, const float* __restrict__ Wk, const float* __restrict__ Wv,
    const float* __restrict__ bq, const float* __restrict__ bk, const float* __restrict__ bv,
    float* __restrict__ q, float* __restrict__ k, float* __restrict__ v) {
    int wave = threadIdx.x >> 6;
    int lane = threadIdx.x & 63;
    int n = blockIdx.x * 4 + wave;
    if (n >= NN) return;
    float f = feats[n * DIM + lane];
    float aq = bq[lane], ak = bk[lane], av = bv[lane];
    #pragma unroll
    for (int kk = 0; kk < DIM; ++kk) {
        float fk = __shfl(f, kk, 64);
        aq = fmaf(fk, Wq[kk * DIM + lane], aq);
        ak = fmaf(fk, Wk[kk * DIM + lane], ak);
        av = fmaf(fk, Wv[kk * DIM + lane], av);
    }
    q[n * DIM + lane] = aq;
    k[n * DIM + lane] = ak;
    v[n * DIM + lane] = av;
}

// wave per destination node: online softmax over CSR in-edges, gather k/v rows
// writes NORMALIZED aggregation (acc/denom) to agg
__global__ __launch_bounds__(256) void attn_kernel(
    const int* __restrict__ rowptr, const int* __restrict__ csr_src,
    const float* __restrict__ csr_attr,
    const float* __restrict__ q, const float* __restrict__ k,
    const float* __restrict__ v, float* __restrict__ agg) {
    int wave = threadIdx.x >> 6;
    int lane = threadIdx.x & 63;
    int n = blockIdx.x * 4 + wave;
    if (n >= NN) return;

    float qv = q[n * DIM + lane];
    int beg = rowptr[n], end = rowptr[n + 1];

    float m = -INFINITY, den = 0.f, acc = 0.f;
    for (int i = beg; i < end; ++i) {
        int src = csr_src[i];
        float a = csr_attr[i];
        float kv = k[src * DIM + lane];
        float vv = v[src * DIM + lane];
        float p = qv * kv;
        p += __shfl_xor(p, 1, 64);
        p += __shfl_xor(p, 2, 64);
        p += __shfl_xor(p, 4, 64);
        p += __shfl_xor(p, 8, 64);          // all 16 lanes of a head hold the dot
        float s = p * 0.25f * a;
        float mn = fmaxf(m, s);
        float corr = __expf(m - mn);        // first iter: exp(-inf) = 0
        float w = __expf(s - mn);
        den = den * corr + w;
        acc = acc * corr + w * vv;
        m = mn;
    }
    agg[n * DIM + lane] = (den > 0.f) ? acc / den : 0.f;
}

// fused: att = agg@Wo+bo ; x=feats+att ; LN1 ; h=relu(x@W1+b1) ;
//        y=h@W2+b2 ; x2=x+y ; LN2 -> out
__global__ __launch_bounds__(256) void post_kernel(
    const float* __restrict__ feats_in,
    const float* __restrict__ agg,
    const float* __restrict__ Wo, const float* __restrict__ bo,
    const float* __restrict__ W1, const float* __restrict__ b1,
    const float* __restrict__ W2, const float* __restrict__ b2,
    const float* __restrict__ g1, const float* __restrict__ be1,
    const float* __restrict__ g2, const float* __restrict__ be2,
    float* __restrict__ out) {
    int wave = threadIdx.x >> 6;
    int lane = threadIdx.x & 63;
    int n = blockIdx.x * 4 + wave;
    if (n >= NN) return;

    float a = agg[n * DIM + lane];

    float att = bo[lane];
    #pragma unroll
    for (int kk = 0; kk < DIM; ++kk) {
        float ak = __shfl(a, kk, 64);
        att = fmaf(ak, Wo[kk * DIM + lane], att);
    }
    float x = feats_in[n * DIM + lane] + att;

    float mean = waveReduceSum(x) * (1.f / 64.f);
    float xc = x - mean;
    float var = waveReduceSum(xc * xc) * (1.f / 64.f);
    float fm = xc * rsqrtf(var + LN_EPS) * g1[lane] + be1[lane];

    float h = b1[lane];
    #pragma unroll
    for (int kk = 0; kk < DIM; ++kk) {
        float fk = __shfl(fm, kk, 64);
        h = fmaf(fk, W1[kk * DIM + lane], h);
    }
    h = fmaxf(h, 0.f);

    float y = b2[lane];
    #pragma unroll
    for (int kk = 0; kk < DIM; ++kk) {
        float hk = __shfl(h, kk, 64);
        y = fmaf(hk, W2[kk * DIM + lane], y);
    }
    float x2 = fm + y;

    float mean2 = waveReduceSum(x2) * (1.f / 64.f);
    float xc2 = x2 - mean2;
    float var2 = waveReduceSum(xc2 * xc2) * (1.f / 64.f);
    out[n * DIM + lane] = xc2 * rsqrtf(var2 + LN_EPS) * g2[lane] + be2[lane];
}

extern "C" void kernel_launch(void* const* d_in, const int* in_sizes, int n_in,
                              void* d_out, int out_size, void* d_ws, size_t ws_size,
                              hipStream_t stream) {
    const float* feats = (const float*)d_in[0];
    const int*   ei    = (const int*)d_in[1];
    const float* attr  = (const float*)d_in[2];
    const float* Wq = (const float*)d_in[3];
    const float* Wk = (const float*)d_in[4];
    const float* Wv = (const float*)d_in[5];
    const float* Wo = (const float*)d_in[6];
    const float* W1 = (const float*)d_in[7];
    const float* W2 = (const float*)d_in[8];
    const float* bq = (const float*)d_in[9];
    const float* bk = (const float*)d_in[10];
    const float* bv = (const float*)d_in[11];
    const float* bo = (const float*)d_in[12];
    const float* b1 = (const float*)d_in[13];
    const float* b2 = (const float*)d_in[14];
    const float* g1  = (const float*)d_in[15];
    const float* be1 = (const float*)d_in[16];
    const float* g2  = (const float*)d_in[17];
    const float* be2 = (const float*)d_in[18];

    float* out = (float*)d_out;
    float* ws = (float*)d_ws;

    const size_t ND = (size_t)NN * DIM;
    float* q   = ws;
    float* k   = ws + ND;
    float* v   = ws + 2 * ND;
    float* agg = ws + 3 * ND;

    int* wi = (int*)(ws + 4 * ND);
    int* deg      = wi;                    // NN
    int* cursor   = wi + NN;               // NN   (zeroed together with deg)
    int* tmp      = wi + 2 * NN;           // NN
    int* bsum     = wi + 3 * NN;           // 256
    int* rowptr   = wi + 3 * NN + 256;     // NN+1
    int* csr_src  = rowptr + NN + 1;       // E
    float* csr_attr = (float*)(csr_src + NEDGE); // E

    // ---- CSR build (graph constant across layers) ----
    zero_kernel<<<(2 * NN + 255) / 256, 256, 0, stream>>>(deg, 2 * NN);
    deg_kernel<<<(NEDGE + 255) / 256, 256, 0, stream>>>(ei, deg);
    scan1_kernel<<<SCAN_BLOCKS, 256, 0, stream>>>(deg, tmp, bsum);
    scan2_kernel<<<1, 256, 0, stream>>>(bsum);
    scan3_kernel<<<SCAN_BLOCKS, 256, 0, stream>>>(tmp, bsum, rowptr);
    fill_kernel<<<(NEDGE + 255) / 256, 256, 0, stream>>>(ei, attr, rowptr, cursor,
                                                         csr_src, csr_attr);

    const float* fin = feats;
    for (int l = 0; l < NLAYER; ++l) {
        const size_t wOff = (size_t)l * DIM * DIM;
        const size_t bOff = (size_t)l * DIM;

        qkv_kernel<<<NN / 4, 256, 0, stream>>>(
            fin, Wq + wOff, Wk + wOff, Wv + wOff,
            bq + bOff, bk + bOff, bv + bOff, q, k, v);

        attn_kernel<<<NN / 4, 256, 0, stream>>>(rowptr, csr_src, csr_attr,
                                                q, k, v, agg);

        post_kernel<<<NN / 4, 256, 0, stream>>>(
            fin, agg,
            Wo + wOff, bo + bOff, W1 + wOff, b1 + bOff, W2 + wOff, b2 + bOff,
            g1 + bOff, be1 + bOff, g2 + bOff, be2 + bOff,
            out + (size_t)l * ND);

        fin = out + (size_t)l * ND;
    }
}

// Round 3
// 846.541 us; speedup vs baseline: 2.2141x; 1.2294x over previous
//
#include <hip/hip_runtime.h>

#define NN 50000      // nodes
#define DIM 64        // feature dim
#define NHEAD 4
#define NEDGE 800000
#define NLAYER 3
#define LN_EPS 1e-5f
#define SCAN_BLOCKS ((NN + 255) / 256)   // 196

__device__ __forceinline__ float waveReduceSum(float x) {
    x += __shfl_xor(x, 32, 64);
    x += __shfl_xor(x, 16, 64);
    x += __shfl_xor(x, 8, 64);
    x += __shfl_xor(x, 4, 64);
    x += __shfl_xor(x, 2, 64);
    x += __shfl_xor(x, 1, 64);
    return x;
}

// wave-uniform broadcast of lane l's x via v_readlane (VALU pipe, no LDS op).
// l must be a compile-time constant (use inside fully-unrolled loops).
__device__ __forceinline__ float bcast(float x, int l) {
    return __uint_as_float(__builtin_amdgcn_readlane(__float_as_uint(x), l));
}

// ---------------- CSR build (once; graph identical across layers) ----------

__global__ __launch_bounds__(256) void zero_kernel(int* __restrict__ p, int n) {
    int i = blockIdx.x * blockDim.x + threadIdx.x;
    if (i < n) p[i] = 0;
}

__global__ __launch_bounds__(256) void deg_kernel(const int* __restrict__ ei,
                                                  int* __restrict__ deg) {
    int e = blockIdx.x * blockDim.x + threadIdx.x;
    if (e < NEDGE) atomicAdd(&deg[ei[NEDGE + e]], 1);
}

__global__ __launch_bounds__(256) void scan1_kernel(const int* __restrict__ deg,
                                                    int* __restrict__ tmp,
                                                    int* __restrict__ bsum) {
    __shared__ int s[256];
    int t = threadIdx.x;
    int i = blockIdx.x * 256 + t;
    int v = (i < NN) ? deg[i] : 0;
    s[t] = v;
    __syncthreads();
    for (int off = 1; off < 256; off <<= 1) {
        int x = (t >= off) ? s[t - off] : 0;
        __syncthreads();
        s[t] += x;
        __syncthreads();
    }
    if (i < NN) tmp[i] = s[t] - v;           // exclusive
    if (t == 255) bsum[blockIdx.x] = s[255]; // inclusive block total
}

__global__ __launch_bounds__(256) void scan2_kernel(int* __restrict__ bsum) {
    __shared__ int s[256];
    int t = threadIdx.x;
    int v = (t < SCAN_BLOCKS) ? bsum[t] : 0;
    s[t] = v;
    __syncthreads();
    for (int off = 1; off < 256; off <<= 1) {
        int x = (t >= off) ? s[t - off] : 0;
        __syncthreads();
        s[t] += x;
        __syncthreads();
    }
    if (t < SCAN_BLOCKS) bsum[t] = s[t] - v; // exclusive
}

__global__ __launch_bounds__(256) void scan3_kernel(const int* __restrict__ tmp,
                                                    const int* __restrict__ bsum,
                                                    int* __restrict__ rowptr) {
    int i = blockIdx.x * 256 + threadIdx.x;
    if (i < NN) rowptr[i] = tmp[i] + bsum[i >> 8];
    if (i == 0) rowptr[NN] = NEDGE;
}

__global__ __launch_bounds__(256) void fill_kernel(const int* __restrict__ ei,
                                                   const float* __restrict__ attr,
                                                   const int* __restrict__ rowptr,
                                                   int* __restrict__ cursor,
                                                   int* __restrict__ csr_src,
                                                   float* __restrict__ csr_attr) {
    int e = blockIdx.x * blockDim.x + threadIdx.x;
    if (e >= NEDGE) return;
    int src = ei[e];
    int dst = ei[NEDGE + e];
    int pos = atomicAdd(&cursor[dst], 1);
    int idx = rowptr[dst] + pos;
    csr_src[idx] = src;
    csr_attr[idx] = attr[e];
}

// ---------------- per-layer kernels ----------------------------------------

// q,k,v = feats @ W{q,k,v} + b ; wave handles 2 rows, lane j owns output col j
__global__ __launch_bounds__(256) void qkv_kernel(
    const float* __restrict__ feats,
    const float* __restrict__ Wq, const float* __restrict__ Wk, const float* __restrict__ Wv,
    const float* __restrict__ bq, const float* __restrict__ bk, const float* __restrict__ bv,
    float* __restrict__ q, float* __restrict__ k, float* __restrict__ v) {
    int wave = threadIdx.x >> 6;
    int lane = threadIdx.x & 63;
    int n = blockIdx.x * 8 + wave * 2;          // 2 rows per wave
    float f0 = feats[n * DIM + lane];
    float f1 = feats[(n + 1) * DIM + lane];
    float q0 = bq[lane], k0 = bk[lane], v0 = bv[lane];
    float q1 = q0, k1 = k0, v1 = v0;
    #pragma unroll
    for (int kk = 0; kk < DIM; ++kk) {
        float wq = Wq[kk * DIM + lane];
        float wk = Wk[kk * DIM + lane];
        float wv = Wv[kk * DIM + lane];
        float x0 = bcast(f0, kk);
        float x1 = bcast(f1, kk);
        q0 = fmaf(x0, wq, q0); k0 = fmaf(x0, wk, k0); v0 = fmaf(x0, wv, v0);
        q1 = fmaf(x1, wq, q1); k1 = fmaf(x1, wk, k1); v1 = fmaf(x1, wv, v1);
    }
    q[n * DIM + lane] = q0; k[n * DIM + lane] = k0; v[n * DIM + lane] = v0;
    q[(n + 1) * DIM + lane] = q1; k[(n + 1) * DIM + lane] = k1; v[(n + 1) * DIM + lane] = v1;
}

// wave per destination node. Split-wave: lanes 0-31 process edge i, lanes 32-63
// edge i+1; each lane owns 2 columns (float2). No max subtraction (scores are
// O(1) here; exp is safe and softmax is shift-invariant).
__global__ __launch_bounds__(256) void attn_kernel(
    const int* __restrict__ rowptr, const int* __restrict__ csr_src,
    const float* __restrict__ csr_attr,
    const float* __restrict__ q, const float* __restrict__ k,
    const float* __restrict__ v, float* __restrict__ agg) {
    int wave = threadIdx.x >> 6;
    int lane = threadIdx.x & 63;
    int half = lane >> 5;                   // which edge of the pair
    int sl = lane & 31;                     // 2*sl, 2*sl+1 = owned columns
    int n = blockIdx.x * 4 + wave;
    if (n >= NN) return;

    float2 qv = *(const float2*)&q[n * DIM + 2 * sl];
    int beg = rowptr[n], end = rowptr[n + 1];
    int nb = end - beg;

    float denom = 0.f;
    float ax = 0.f, ay = 0.f;

    for (int base = 0; base < nb; base += 64) {
        int m = min(64, nb - base);
        int src_l = 0; float attr_l = 0.f;
        if (lane < m) {
            src_l = csr_src[beg + base + lane];
            attr_l = csr_attr[beg + base + lane];
        }
        #pragma unroll 2
        for (int ii = 0; ii < m; ii += 2) {
            int e = ii + half;
            bool valid = e < m;
            int ec = valid ? e : 0;
            int src = __shfl(src_l, ec, 64);
            float a = __shfl(attr_l, ec, 64);
            float2 kv = *(const float2*)&k[src * DIM + 2 * sl];
            float2 vv = *(const float2*)&v[src * DIM + 2 * sl];
            float p = fmaf(qv.x, kv.x, qv.y * kv.y);
            p += __shfl_xor(p, 1, 64);
            p += __shfl_xor(p, 2, 64);
            p += __shfl_xor(p, 4, 64);      // 8-lane group = one 16-col head
            float w = valid ? __expf(p * 0.25f * a) : 0.f;
            denom += w;
            ax = fmaf(w, vv.x, ax);
            ay = fmaf(w, vv.y, ay);
        }
    }
    // combine the two half-wave accumulators
    ax += __shfl_xor(ax, 32, 64);
    ay += __shfl_xor(ay, 32, 64);
    denom += __shfl_xor(denom, 32, 64);

    if (half == 0) {
        float inv = (denom > 0.f) ? 1.f / denom : 0.f;
        float2 o; o.x = ax * inv; o.y = ay * inv;
        *(float2*)&agg[n * DIM + 2 * sl] = o;
    }
}

// fused: att = agg@Wo+bo ; x=feats+att ; LN1 ; h=relu(x@W1+b1) ;
//        y=h@W2+b2 ; x2=x+y ; LN2 -> out
__global__ __launch_bounds__(256) void post_kernel(
    const float* __restrict__ feats_in,
    const float* __restrict__ agg,
    const float* __restrict__ Wo, const float* __restrict__ bo,
    const float* __restrict__ W1, const float* __restrict__ b1,
    const float* __restrict__ W2, const float* __restrict__ b2,
    const float* __restrict__ g1, const float* __restrict__ be1,
    const float* __restrict__ g2, const float* __restrict__ be2,
    float* __restrict__ out) {
    int wave = threadIdx.x >> 6;
    int lane = threadIdx.x & 63;
    int n = blockIdx.x * 4 + wave;
    if (n >= NN) return;

    float a = agg[n * DIM + lane];

    float att = bo[lane];
    #pragma unroll
    for (int kk = 0; kk < DIM; ++kk) {
        att = fmaf(bcast(a, kk), Wo[kk * DIM + lane], att);
    }
    float x = feats_in[n * DIM + lane] + att;

    float mean = waveReduceSum(x) * (1.f / 64.f);
    float xc = x - mean;
    float var = waveReduceSum(xc * xc) * (1.f / 64.f);
    float fm = xc * rsqrtf(var + LN_EPS) * g1[lane] + be1[lane];

    float h = b1[lane];
    #pragma unroll
    for (int kk = 0; kk < DIM; ++kk) {
        h = fmaf(bcast(fm, kk), W1[kk * DIM + lane], h);
    }
    h = fmaxf(h, 0.f);

    float y = b2[lane];
    #pragma unroll
    for (int kk = 0; kk < DIM; ++kk) {
        y = fmaf(bcast(h, kk), W2[kk * DIM + lane], y);
    }
    float x2 = fm + y;

    float mean2 = waveReduceSum(x2) * (1.f / 64.f);
    float xc2 = x2 - mean2;
    float var2 = waveReduceSum(xc2 * xc2) * (1.f / 64.f);
    out[n * DIM + lane] = xc2 * rsqrtf(var2 + LN_EPS) * g2[lane] + be2[lane];
}

extern "C" void kernel_launch(void* const* d_in, const int* in_sizes, int n_in,
                              void* d_out, int out_size, void* d_ws, size_t ws_size,
                              hipStream_t stream) {
    const float* feats = (const float*)d_in[0];
    const int*   ei    = (const int*)d_in[1];
    const float* attr  = (const float*)d_in[2];
    const float* Wq = (const float*)d_in[3];
    const float* Wk = (const float*)d_in[4];
    const float* Wv = (const float*)d_in[5];
    const float* Wo = (const float*)d_in[6];
    const float* W1 = (const float*)d_in[7];
    const float* W2 = (const float*)d_in[8];
    const float* bq = (const float*)d_in[9];
    const float* bk = (const float*)d_in[10];
    const float* bv = (const float*)d_in[11];
    const float* bo = (const float*)d_in[12];
    const float* b1 = (const float*)d_in[13];
    const float* b2 = (const float*)d_in[14];
    const float* g1  = (const float*)d_in[15];
    const float* be1 = (const float*)d_in[16];
    const float* g2  = (const float*)d_in[17];
    const float* be2 = (const float*)d_in[18];

    float* out = (float*)d_out;
    float* ws = (float*)d_ws;

    const size_t ND = (size_t)NN * DIM;
    float* q   = ws;
    float* k   = ws + ND;
    float* v   = ws + 2 * ND;
    float* agg = ws + 3 * ND;

    int* wi = (int*)(ws + 4 * ND);
    int* deg      = wi;                    // NN
    int* cursor   = wi + NN;               // NN   (zeroed together with deg)
    int* tmp      = wi + 2 * NN;           // NN
    int* bsum     = wi + 3 * NN;           // 256
    int* rowptr   = wi + 3 * NN + 256;     // NN+1
    int* csr_src  = rowptr + NN + 1;       // E
    float* csr_attr = (float*)(csr_src + NEDGE); // E

    // ---- CSR build (graph constant across layers) ----
    zero_kernel<<<(2 * NN + 255) / 256, 256, 0, stream>>>(deg, 2 * NN);
    deg_kernel<<<(NEDGE + 255) / 256, 256, 0, stream>>>(ei, deg);
    scan1_kernel<<<SCAN_BLOCKS, 256, 0, stream>>>(deg, tmp, bsum);
    scan2_kernel<<<1, 256, 0, stream>>>(bsum);
    scan3_kernel<<<SCAN_BLOCKS, 256, 0, stream>>>(tmp, bsum, rowptr);
    fill_kernel<<<(NEDGE + 255) / 256, 256, 0, stream>>>(ei, attr, rowptr, cursor,
                                                         csr_src, csr_attr);

    const float* fin = feats;
    for (int l = 0; l < NLAYER; ++l) {
        const size_t wOff = (size_t)l * DIM * DIM;
        const size_t bOff = (size_t)l * DIM;

        qkv_kernel<<<NN / 8, 256, 0, stream>>>(
            fin, Wq + wOff, Wk + wOff, Wv + wOff,
            bq + bOff, bk + bOff, bv + bOff, q, k, v);

        attn_kernel<<<NN / 4, 256, 0, stream>>>(rowptr, csr_src, csr_attr,
                                                q, k, v, agg);

        post_kernel<<<NN / 4, 256, 0, stream>>>(
            fin, agg,
            Wo + wOff, bo + bOff, W1 + wOff, b1 + bOff, W2 + wOff, b2 + bOff,
            g1 + bOff, be1 + bOff, g2 + bOff, be2 + bOff,
            out + (size_t)l * ND);

        fin = out + (size_t)l * ND;
    }
}

// Round 4
// 611.470 us; speedup vs baseline: 3.0653x; 1.3844x over previous
//
#include <hip/hip_runtime.h>

#define NN 50000      // nodes
#define DIM 64        // feature dim
#define NHEAD 4
#define NEDGE 800000
#define NLAYER 3
#define LN_EPS 1e-5f
#define SCAN_BLOCKS ((NN + 255) / 256)   // 196
#define ROWS 8                           // rows per wave in qkv/post

__device__ __forceinline__ float waveReduceSum(float x) {
    x += __shfl_xor(x, 32, 64);
    x += __shfl_xor(x, 16, 64);
    x += __shfl_xor(x, 8, 64);
    x += __shfl_xor(x, 4, 64);
    x += __shfl_xor(x, 2, 64);
    x += __shfl_xor(x, 1, 64);
    return x;
}

// wave-uniform broadcast of lane l's x via v_readlane (VALU pipe, no LDS op).
// l must be a compile-time constant (use inside fully-unrolled loops).
__device__ __forceinline__ float bcast(float x, int l) {
    return __uint_as_float(__builtin_amdgcn_readlane(__float_as_uint(x), l));
}

// ---------------- CSR build (once; graph identical across layers) ----------

__global__ __launch_bounds__(256) void zero_kernel(int* __restrict__ p, int n) {
    int i = blockIdx.x * blockDim.x + threadIdx.x;
    if (i < n) p[i] = 0;
}

__global__ __launch_bounds__(256) void deg_kernel(const int* __restrict__ ei,
                                                  int* __restrict__ deg) {
    int e = blockIdx.x * blockDim.x + threadIdx.x;
    if (e < NEDGE) atomicAdd(&deg[ei[NEDGE + e]], 1);
}

__global__ __launch_bounds__(256) void scan1_kernel(const int* __restrict__ deg,
                                                    int* __restrict__ tmp,
                                                    int* __restrict__ bsum) {
    __shared__ int s[256];
    int t = threadIdx.x;
    int i = blockIdx.x * 256 + t;
    int v = (i < NN) ? deg[i] : 0;
    s[t] = v;
    __syncthreads();
    for (int off = 1; off < 256; off <<= 1) {
        int x = (t >= off) ? s[t - off] : 0;
        __syncthreads();
        s[t] += x;
        __syncthreads();
    }
    if (i < NN) tmp[i] = s[t] - v;           // exclusive
    if (t == 255) bsum[blockIdx.x] = s[255]; // inclusive block total
}

__global__ __launch_bounds__(256) void scan2_kernel(int* __restrict__ bsum) {
    __shared__ int s[256];
    int t = threadIdx.x;
    int v = (t < SCAN_BLOCKS) ? bsum[t] : 0;
    s[t] = v;
    __syncthreads();
    for (int off = 1; off < 256; off <<= 1) {
        int x = (t >= off) ? s[t - off] : 0;
        __syncthreads();
        s[t] += x;
        __syncthreads();
    }
    if (t < SCAN_BLOCKS) bsum[t] = s[t] - v; // exclusive
}

__global__ __launch_bounds__(256) void scan3_kernel(const int* __restrict__ tmp,
                                                    const int* __restrict__ bsum,
                                                    int* __restrict__ rowptr) {
    int i = blockIdx.x * 256 + threadIdx.x;
    if (i < NN) rowptr[i] = tmp[i] + bsum[i >> 8];
    if (i == 0) rowptr[NN] = NEDGE;
}

__global__ __launch_bounds__(256) void fill_kernel(const int* __restrict__ ei,
                                                   const float* __restrict__ attr,
                                                   const int* __restrict__ rowptr,
                                                   int* __restrict__ cursor,
                                                   int* __restrict__ csr_src,
                                                   float* __restrict__ csr_attr) {
    int e = blockIdx.x * blockDim.x + threadIdx.x;
    if (e >= NEDGE) return;
    int src = ei[e];
    int dst = ei[NEDGE + e];
    int pos = atomicAdd(&cursor[dst], 1);
    int idx = rowptr[dst] + pos;
    csr_src[idx] = src;
    csr_attr[idx] = attr[e];
}

// ---------------- per-layer kernels ----------------------------------------

// q,k,v = feats @ W{q,k,v} + b ; wave handles ROWS rows, lane j owns col j
__global__ __launch_bounds__(256) void qkv_kernel(
    const float* __restrict__ feats,
    const float* __restrict__ Wq, const float* __restrict__ Wk, const float* __restrict__ Wv,
    const float* __restrict__ bq, const float* __restrict__ bk, const float* __restrict__ bv,
    float* __restrict__ q, float* __restrict__ k, float* __restrict__ v) {
    int wave = threadIdx.x >> 6;
    int lane = threadIdx.x & 63;
    int n0 = (blockIdx.x * 4 + wave) * ROWS;

    float f[ROWS], qa[ROWS], ka[ROWS], va[ROWS];
    float biq = bq[lane], bik = bk[lane], biv = bv[lane];
    #pragma unroll
    for (int r = 0; r < ROWS; ++r) {
        int n = min(n0 + r, NN - 1);        // clamp (stores are guarded)
        f[r] = feats[n * DIM + lane];
        qa[r] = biq; ka[r] = bik; va[r] = biv;
    }
    #pragma unroll
    for (int kk = 0; kk < DIM; ++kk) {
        float wq = Wq[kk * DIM + lane];
        float wk = Wk[kk * DIM + lane];
        float wv = Wv[kk * DIM + lane];
        #pragma unroll
        for (int r = 0; r < ROWS; ++r) {
            float x = bcast(f[r], kk);
            qa[r] = fmaf(x, wq, qa[r]);
            ka[r] = fmaf(x, wk, ka[r]);
            va[r] = fmaf(x, wv, va[r]);
        }
    }
    #pragma unroll
    for (int r = 0; r < ROWS; ++r) {
        int n = n0 + r;
        if (n < NN) {
            q[n * DIM + lane] = qa[r];
            k[n * DIM + lane] = ka[r];
            v[n * DIM + lane] = va[r];
        }
    }
}

// wave per destination node. Split-wave: lanes 0-31 process edge i, lanes 32-63
// edge i+1; each lane owns 2 columns (float2). No max subtraction (scores are
// O(1) here; exp is safe and softmax is shift-invariant).
__global__ __launch_bounds__(256) void attn_kernel(
    const int* __restrict__ rowptr, const int* __restrict__ csr_src,
    const float* __restrict__ csr_attr,
    const float* __restrict__ q, const float* __restrict__ k,
    const float* __restrict__ v, float* __restrict__ agg) {
    int wave = threadIdx.x >> 6;
    int lane = threadIdx.x & 63;
    int half = lane >> 5;                   // which edge of the pair
    int sl = lane & 31;                     // 2*sl, 2*sl+1 = owned columns
    int n = blockIdx.x * 4 + wave;
    if (n >= NN) return;

    float2 qv = *(const float2*)&q[n * DIM + 2 * sl];
    int beg = rowptr[n], end = rowptr[n + 1];
    int nb = end - beg;

    float denom = 0.f;
    float ax = 0.f, ay = 0.f;

    for (int base = 0; base < nb; base += 64) {
        int m = min(64, nb - base);
        int src_l = 0; float attr_l = 0.f;
        if (lane < m) {
            src_l = csr_src[beg + base + lane];
            attr_l = csr_attr[beg + base + lane];
        }
        #pragma unroll 2
        for (int ii = 0; ii < m; ii += 2) {
            int e = ii + half;
            bool valid = e < m;
            int ec = valid ? e : 0;
            int src = __shfl(src_l, ec, 64);
            float a = __shfl(attr_l, ec, 64);
            float2 kv = *(const float2*)&k[src * DIM + 2 * sl];
            float2 vv = *(const float2*)&v[src * DIM + 2 * sl];
            float p = fmaf(qv.x, kv.x, qv.y * kv.y);
            p += __shfl_xor(p, 1, 64);
            p += __shfl_xor(p, 2, 64);
            p += __shfl_xor(p, 4, 64);      // 8-lane group = one 16-col head
            float w = valid ? __expf(p * 0.25f * a) : 0.f;
            denom += w;
            ax = fmaf(w, vv.x, ax);
            ay = fmaf(w, vv.y, ay);
        }
    }
    // combine the two half-wave accumulators
    ax += __shfl_xor(ax, 32, 64);
    ay += __shfl_xor(ay, 32, 64);
    denom += __shfl_xor(denom, 32, 64);

    if (half == 0) {
        float inv = (denom > 0.f) ? 1.f / denom : 0.f;
        float2 o; o.x = ax * inv; o.y = ay * inv;
        *(float2*)&agg[n * DIM + 2 * sl] = o;
    }
}

// fused per-row tail, ROWS rows per wave:
// att = agg@Wo+bo ; x=feats+att ; LN1 ; h=relu(x@W1+b1) ; y=h@W2+b2 ; LN2(fm+y)
__global__ __launch_bounds__(256) void post_kernel(
    const float* __restrict__ feats_in,
    const float* __restrict__ agg,
    const float* __restrict__ Wo, const float* __restrict__ bo,
    const float* __restrict__ W1, const float* __restrict__ b1,
    const float* __restrict__ W2, const float* __restrict__ b2,
    const float* __restrict__ g1, const float* __restrict__ be1,
    const float* __restrict__ g2, const float* __restrict__ be2,
    float* __restrict__ out) {
    int wave = threadIdx.x >> 6;
    int lane = threadIdx.x & 63;
    int n0 = (blockIdx.x * 4 + wave) * ROWS;

    float acc[ROWS], xin[ROWS];
    float bio = bo[lane];
    #pragma unroll
    for (int r = 0; r < ROWS; ++r) {
        int n = min(n0 + r, NN - 1);
        xin[r] = agg[n * DIM + lane];       // reuse: attention output first
        acc[r] = bio;
    }
    #pragma unroll
    for (int kk = 0; kk < DIM; ++kk) {
        float w = Wo[kk * DIM + lane];
        #pragma unroll
        for (int r = 0; r < ROWS; ++r)
            acc[r] = fmaf(bcast(xin[r], kk), w, acc[r]);
    }
    // x = feats + att ; LN1 -> fm (kept in xin)
    float gg1 = g1[lane], bb1 = be1[lane];
    #pragma unroll
    for (int r = 0; r < ROWS; ++r) {
        int n = min(n0 + r, NN - 1);
        float x = feats_in[n * DIM + lane] + acc[r];
        float mean = waveReduceSum(x) * (1.f / 64.f);
        float xc = x - mean;
        float var = waveReduceSum(xc * xc) * (1.f / 64.f);
        xin[r] = xc * rsqrtf(var + LN_EPS) * gg1 + bb1;   // fm
    }
    // h = relu(fm@W1+b1)
    float bi1 = b1[lane];
    #pragma unroll
    for (int r = 0; r < ROWS; ++r) acc[r] = bi1;
    #pragma unroll
    for (int kk = 0; kk < DIM; ++kk) {
        float w = W1[kk * DIM + lane];
        #pragma unroll
        for (int r = 0; r < ROWS; ++r)
            acc[r] = fmaf(bcast(xin[r], kk), w, acc[r]);
    }
    float h[ROWS];
    #pragma unroll
    for (int r = 0; r < ROWS; ++r) h[r] = fmaxf(acc[r], 0.f);
    // y = h@W2+b2
    float bi2 = b2[lane];
    #pragma unroll
    for (int r = 0; r < ROWS; ++r) acc[r] = bi2;
    #pragma unroll
    for (int kk = 0; kk < DIM; ++kk) {
        float w = W2[kk * DIM + lane];
        #pragma unroll
        for (int r = 0; r < ROWS; ++r)
            acc[r] = fmaf(bcast(h[r], kk), w, acc[r]);
    }
    // x2 = fm + y ; LN2 -> out
    float gg2 = g2[lane], bb2 = be2[lane];
    #pragma unroll
    for (int r = 0; r < ROWS; ++r) {
        int n = n0 + r;
        float x2 = xin[r] + acc[r];
        float mean = waveReduceSum(x2) * (1.f / 64.f);
        float xc = x2 - mean;
        float var = waveReduceSum(xc * xc) * (1.f / 64.f);
        if (n < NN)
            out[n * DIM + lane] = xc * rsqrtf(var + LN_EPS) * gg2 + bb2;
    }
}

extern "C" void kernel_launch(void* const* d_in, const int* in_sizes, int n_in,
                              void* d_out, int out_size, void* d_ws, size_t ws_size,
                              hipStream_t stream) {
    const float* feats = (const float*)d_in[0];
    const int*   ei    = (const int*)d_in[1];
    const float* attr  = (const float*)d_in[2];
    const float* Wq = (const float*)d_in[3];
    const float* Wk = (const float*)d_in[4];
    const float* Wv = (const float*)d_in[5];
    const float* Wo = (const float*)d_in[6];
    const float* W1 = (const float*)d_in[7];
    const float* W2 = (const float*)d_in[8];
    const float* bq = (const float*)d_in[9];
    const float* bk = (const float*)d_in[10];
    const float* bv = (const float*)d_in[11];
    const float* bo = (const float*)d_in[12];
    const float* b1 = (const float*)d_in[13];
    const float* b2 = (const float*)d_in[14];
    const float* g1  = (const float*)d_in[15];
    const float* be1 = (const float*)d_in[16];
    const float* g2  = (const float*)d_in[17];
    const float* be2 = (const float*)d_in[18];

    float* out = (float*)d_out;
    float* ws = (float*)d_ws;

    const size_t ND = (size_t)NN * DIM;
    float* q   = ws;
    float* k   = ws + ND;
    float* v   = ws + 2 * ND;
    float* agg = ws + 3 * ND;

    int* wi = (int*)(ws + 4 * ND);
    int* deg      = wi;                    // NN
    int* cursor   = wi + NN;               // NN   (zeroed together with deg)
    int* tmp      = wi + 2 * NN;           // NN
    int* bsum     = wi + 3 * NN;           // 256
    int* rowptr   = wi + 3 * NN + 256;     // NN+1
    int* csr_src  = rowptr + NN + 1;       // E
    float* csr_attr = (float*)(csr_src + NEDGE); // E

    // ---- CSR build (graph constant across layers) ----
    zero_kernel<<<(2 * NN + 255) / 256, 256, 0, stream>>>(deg, 2 * NN);
    deg_kernel<<<(NEDGE + 255) / 256, 256, 0, stream>>>(ei, deg);
    scan1_kernel<<<SCAN_BLOCKS, 256, 0, stream>>>(deg, tmp, bsum);
    scan2_kernel<<<1, 256, 0, stream>>>(bsum);
    scan3_kernel<<<SCAN_BLOCKS, 256, 0, stream>>>(tmp, bsum, rowptr);
    fill_kernel<<<(NEDGE + 255) / 256, 256, 0, stream>>>(ei, attr, rowptr, cursor,
                                                         csr_src, csr_attr);

    const int rowBlocks = (NN + 4 * ROWS - 1) / (4 * ROWS);
    const float* fin = feats;
    for (int l = 0; l < NLAYER; ++l) {
        const size_t wOff = (size_t)l * DIM * DIM;
        const size_t bOff = (size_t)l * DIM;

        qkv_kernel<<<rowBlocks, 256, 0, stream>>>(
            fin, Wq + wOff, Wk + wOff, Wv + wOff,
            bq + bOff, bk + bOff, bv + bOff, q, k, v);

        attn_kernel<<<NN / 4, 256, 0, stream>>>(rowptr, csr_src, csr_attr,
                                                q, k, v, agg);

        post_kernel<<<rowBlocks, 256, 0, stream>>>(
            fin, agg,
            Wo + wOff, bo + bOff, W1 + wOff, b1 + bOff, W2 + wOff, b2 + bOff,
            g1 + bOff, be1 + bOff, g2 + bOff, be2 + bOff,
            out + (size_t)l * ND);

        fin = out + (size_t)l * ND;
    }
}

// Round 5
// 547.445 us; speedup vs baseline: 3.4238x; 1.1170x over previous
//
#include <hip/hip_runtime.h>

#define NN 50000      // nodes
#define DIM 64        // feature dim
#define NHEAD 4
#define NEDGE 800000
#define NLAYER 3
#define LN_EPS 1e-5f
#define SCAN_BLOCKS ((NN + 255) / 256)   // 196
#define ROWS 8                           // rows per wave in qkv/post

__device__ __forceinline__ float waveReduceSum(float x) {
    x += __shfl_xor(x, 32, 64);
    x += __shfl_xor(x, 16, 64);
    x += __shfl_xor(x, 8, 64);
    x += __shfl_xor(x, 4, 64);
    x += __shfl_xor(x, 2, 64);
    x += __shfl_xor(x, 1, 64);
    return x;
}

// wave-uniform broadcast of lane l's x via v_readlane (VALU pipe, no LDS op).
__device__ __forceinline__ float bcast(float x, int l) {
    return __uint_as_float(__builtin_amdgcn_readlane(__float_as_uint(x), l));
}

// f32 -> bf16 bits, round-to-nearest-even
__device__ __forceinline__ unsigned int bf16rtn(float x) {
    unsigned int u = __float_as_uint(x);
    return (u + 0x7FFFu + ((u >> 16) & 1u)) >> 16;
}

// ---------------- CSR build (once; graph identical across layers) ----------

__global__ __launch_bounds__(256) void zero_kernel(int* __restrict__ p, int n) {
    int i = blockIdx.x * blockDim.x + threadIdx.x;
    if (i < n) p[i] = 0;
}

__global__ __launch_bounds__(256) void deg_kernel(const int* __restrict__ ei,
                                                  int* __restrict__ deg) {
    int e = blockIdx.x * blockDim.x + threadIdx.x;
    if (e < NEDGE) atomicAdd(&deg[ei[NEDGE + e]], 1);
}

__global__ __launch_bounds__(256) void scan1_kernel(const int* __restrict__ deg,
                                                    int* __restrict__ tmp,
                                                    int* __restrict__ bsum) {
    __shared__ int s[256];
    int t = threadIdx.x;
    int i = blockIdx.x * 256 + t;
    int v = (i < NN) ? deg[i] : 0;
    s[t] = v;
    __syncthreads();
    for (int off = 1; off < 256; off <<= 1) {
        int x = (t >= off) ? s[t - off] : 0;
        __syncthreads();
        s[t] += x;
        __syncthreads();
    }
    if (i < NN) tmp[i] = s[t] - v;           // exclusive
    if (t == 255) bsum[blockIdx.x] = s[255]; // inclusive block total
}

__global__ __launch_bounds__(256) void scan2_kernel(int* __restrict__ bsum) {
    __shared__ int s[256];
    int t = threadIdx.x;
    int v = (t < SCAN_BLOCKS) ? bsum[t] : 0;
    s[t] = v;
    __syncthreads();
    for (int off = 1; off < 256; off <<= 1) {
        int x = (t >= off) ? s[t - off] : 0;
        __syncthreads();
        s[t] += x;
        __syncthreads();
    }
    if (t < SCAN_BLOCKS) bsum[t] = s[t] - v; // exclusive
}

__global__ __launch_bounds__(256) void scan3_kernel(const int* __restrict__ tmp,
                                                    const int* __restrict__ bsum,
                                                    int* __restrict__ rowptr) {
    int i = blockIdx.x * 256 + threadIdx.x;
    if (i < NN) rowptr[i] = tmp[i] + bsum[i >> 8];
    if (i == 0) rowptr[NN] = NEDGE;
}

// packed CSR entry: .x = src node, .y = attr bits (one 8B store per edge)
__global__ __launch_bounds__(256) void fill_kernel(const int* __restrict__ ei,
                                                   const float* __restrict__ attr,
                                                   const int* __restrict__ rowptr,
                                                   int* __restrict__ cursor,
                                                   int2* __restrict__ csr) {
    int e = blockIdx.x * blockDim.x + threadIdx.x;
    if (e >= NEDGE) return;
    int src = ei[e];
    int dst = ei[NEDGE + e];
    int pos = atomicAdd(&cursor[dst], 1);
    int2 pk;
    pk.x = src;
    pk.y = __float_as_int(attr[e]);
    csr[rowptr[dst] + pos] = pk;
}

// ---------------- per-layer kernels ----------------------------------------

// q,k,v = feats @ W{q,k,v} + b ; wave handles ROWS rows, lane j owns col j.
// q written f32 PRE-SCALED by 0.25 (softmax scale folded in);
// k,v written as packed bf16x2 (u32 per 2 cols).
__global__ __launch_bounds__(256) void qkv_kernel(
    const float* __restrict__ feats,
    const float* __restrict__ Wq, const float* __restrict__ Wk, const float* __restrict__ Wv,
    const float* __restrict__ bq, const float* __restrict__ bk, const float* __restrict__ bv,
    float* __restrict__ q, unsigned int* __restrict__ kpk, unsigned int* __restrict__ vpk) {
    int wave = threadIdx.x >> 6;
    int lane = threadIdx.x & 63;
    int n0 = (blockIdx.x * 4 + wave) * ROWS;

    float f[ROWS], qa[ROWS], ka[ROWS], va[ROWS];
    float biq = bq[lane], bik = bk[lane], biv = bv[lane];
    #pragma unroll
    for (int r = 0; r < ROWS; ++r) {
        int n = min(n0 + r, NN - 1);        // clamp (stores are guarded)
        f[r] = feats[n * DIM + lane];
        qa[r] = biq; ka[r] = bik; va[r] = biv;
    }
    #pragma unroll
    for (int kk = 0; kk < DIM; ++kk) {
        float wq = Wq[kk * DIM + lane];
        float wk = Wk[kk * DIM + lane];
        float wv = Wv[kk * DIM + lane];
        #pragma unroll
        for (int r = 0; r < ROWS; ++r) {
            float x = bcast(f[r], kk);
            qa[r] = fmaf(x, wq, qa[r]);
            ka[r] = fmaf(x, wk, ka[r]);
            va[r] = fmaf(x, wv, va[r]);
        }
    }
    bool evenLane = (lane & 1) == 0;
    #pragma unroll
    for (int r = 0; r < ROWS; ++r) {
        int n = n0 + r;
        if (n < NN) q[n * DIM + lane] = qa[r] * 0.25f;
        // pack col pairs: even lane holds (b_c | b_{c+1}<<16)
        unsigned int bk_ = bf16rtn(ka[r]);
        unsigned int bv_ = bf16rtn(va[r]);
        unsigned int nk = __shfl_xor(bk_, 1, 64);
        unsigned int nv = __shfl_xor(bv_, 1, 64);
        if (n < NN && evenLane) {
            kpk[n * 32 + (lane >> 1)] = bk_ | (nk << 16);
            vpk[n * 32 + (lane >> 1)] = bv_ | (nv << 16);
        }
    }
}

// wave per destination node; 4 edges in flight (one per 16-lane quarter);
// lane owns 4 columns. k,v gathered as packed bf16 (half the bytes of f32).
__global__ __launch_bounds__(256) void attn_kernel(
    const int* __restrict__ rowptr, const int2* __restrict__ csr,
    const float* __restrict__ q,
    const unsigned int* __restrict__ kpk, const unsigned int* __restrict__ vpk,
    float* __restrict__ agg) {
    int wave = threadIdx.x >> 6;
    int lane = threadIdx.x & 63;
    int quarter = lane >> 4;
    int sl = lane & 15;                     // cols 4sl..4sl+3
    int n = blockIdx.x * 4 + wave;
    if (n >= NN) return;

    float4 qv = *(const float4*)&q[n * DIM + 4 * sl];   // pre-scaled by 0.25
    int beg = rowptr[n], end = rowptr[n + 1];
    int nb = end - beg;

    float denom = 0.f;
    float a0 = 0.f, a1 = 0.f, a2 = 0.f, a3 = 0.f;

    for (int base = 0; base < nb; base += 64) {
        int m = min(64, nb - base);
        int src_l = 0, attr_l = 0;
        if (lane < m) {
            int2 me = csr[beg + base + lane];
            src_l = me.x;
            attr_l = me.y;
        }
        for (int ii = 0; ii < m; ii += 4) {
            int e = ii + quarter;
            bool valid = e < m;
            int ec = valid ? e : 0;
            int src = __shfl(src_l, ec, 64);
            float a = __int_as_float(__shfl(attr_l, ec, 64));
            uint2 ku = *(const uint2*)&kpk[src * 32 + 2 * sl];
            uint2 vu = *(const uint2*)&vpk[src * 32 + 2 * sl];
            // unpack bf16x2 pairs (low bf16 = even col)
            float k0 = __uint_as_float(ku.x << 16);
            float k1 = __uint_as_float(ku.x & 0xFFFF0000u);
            float k2 = __uint_as_float(ku.y << 16);
            float k3 = __uint_as_float(ku.y & 0xFFFF0000u);
            float p = qv.x * k0;
            p = fmaf(qv.y, k1, p);
            p = fmaf(qv.z, k2, p);
            p = fmaf(qv.w, k3, p);
            p += __shfl_xor(p, 1, 64);
            p += __shfl_xor(p, 2, 64);      // 4-lane group = one 16-col head
            float w = valid ? __expf(p * a) : 0.f;
            denom += w;
            float v0 = __uint_as_float(vu.x << 16);
            float v1 = __uint_as_float(vu.x & 0xFFFF0000u);
            float v2 = __uint_as_float(vu.y << 16);
            float v3 = __uint_as_float(vu.y & 0xFFFF0000u);
            a0 = fmaf(w, v0, a0);
            a1 = fmaf(w, v1, a1);
            a2 = fmaf(w, v2, a2);
            a3 = fmaf(w, v3, a3);
        }
    }
    // combine the 4 quarter accumulators
    a0 += __shfl_xor(a0, 16, 64); a0 += __shfl_xor(a0, 32, 64);
    a1 += __shfl_xor(a1, 16, 64); a1 += __shfl_xor(a1, 32, 64);
    a2 += __shfl_xor(a2, 16, 64); a2 += __shfl_xor(a2, 32, 64);
    a3 += __shfl_xor(a3, 16, 64); a3 += __shfl_xor(a3, 32, 64);
    denom += __shfl_xor(denom, 16, 64); denom += __shfl_xor(denom, 32, 64);

    if (quarter == 0) {
        float inv = (denom > 0.f) ? 1.f / denom : 0.f;
        float4 o;
        o.x = a0 * inv; o.y = a1 * inv; o.z = a2 * inv; o.w = a3 * inv;
        *(float4*)&agg[n * DIM + 4 * sl] = o;
    }
}

// fused per-row tail, ROWS rows per wave:
// att = agg@Wo+bo ; x=feats+att ; LN1 ; h=relu(x@W1+b1) ; y=h@W2+b2 ; LN2(fm+y)
__global__ __launch_bounds__(256) void post_kernel(
    const float* __restrict__ feats_in,
    const float* __restrict__ agg,
    const float* __restrict__ Wo, const float* __restrict__ bo,
    const float* __restrict__ W1, const float* __restrict__ b1,
    const float* __restrict__ W2, const float* __restrict__ b2,
    const float* __restrict__ g1, const float* __restrict__ be1,
    const float* __restrict__ g2, const float* __restrict__ be2,
    float* __restrict__ out) {
    int wave = threadIdx.x >> 6;
    int lane = threadIdx.x & 63;
    int n0 = (blockIdx.x * 4 + wave) * ROWS;

    float acc[ROWS], xin[ROWS];
    float bio = bo[lane];
    #pragma unroll
    for (int r = 0; r < ROWS; ++r) {
        int n = min(n0 + r, NN - 1);
        xin[r] = agg[n * DIM + lane];
        acc[r] = bio;
    }
    #pragma unroll
    for (int kk = 0; kk < DIM; ++kk) {
        float w = Wo[kk * DIM + lane];
        #pragma unroll
        for (int r = 0; r < ROWS; ++r)
            acc[r] = fmaf(bcast(xin[r], kk), w, acc[r]);
    }
    // x = feats + att ; LN1 -> fm (kept in xin). one-pass sum/sumsq reduce.
    float gg1 = g1[lane], bb1 = be1[lane];
    #pragma unroll
    for (int r = 0; r < ROWS; ++r) {
        int n = min(n0 + r, NN - 1);
        float x = feats_in[n * DIM + lane] + acc[r];
        float s1 = x, s2 = x * x;
        #pragma unroll
        for (int o = 32; o >= 1; o >>= 1) {
            s1 += __shfl_xor(s1, o, 64);
            s2 += __shfl_xor(s2, o, 64);
        }
        float mean = s1 * (1.f / 64.f);
        float var = fmaf(-mean, mean, s2 * (1.f / 64.f));
        xin[r] = (x - mean) * rsqrtf(var + LN_EPS) * gg1 + bb1;   // fm
    }
    // h = relu(fm@W1+b1)
    float bi1 = b1[lane];
    #pragma unroll
    for (int r = 0; r < ROWS; ++r) acc[r] = bi1;
    #pragma unroll
    for (int kk = 0; kk < DIM; ++kk) {
        float w = W1[kk * DIM + lane];
        #pragma unroll
        for (int r = 0; r < ROWS; ++r)
            acc[r] = fmaf(bcast(xin[r], kk), w, acc[r]);
    }
    float h[ROWS];
    #pragma unroll
    for (int r = 0; r < ROWS; ++r) h[r] = fmaxf(acc[r], 0.f);
    // y = h@W2+b2
    float bi2 = b2[lane];
    #pragma unroll
    for (int r = 0; r < ROWS; ++r) acc[r] = bi2;
    #pragma unroll
    for (int kk = 0; kk < DIM; ++kk) {
        float w = W2[kk * DIM + lane];
        #pragma unroll
        for (int r = 0; r < ROWS; ++r)
            acc[r] = fmaf(bcast(h[r], kk), w, acc[r]);
    }
    // x2 = fm + y ; LN2 -> out
    float gg2 = g2[lane], bb2 = be2[lane];
    #pragma unroll
    for (int r = 0; r < ROWS; ++r) {
        int n = n0 + r;
        float x2 = xin[r] + acc[r];
        float s1 = x2, s2 = x2 * x2;
        #pragma unroll
        for (int o = 32; o >= 1; o >>= 1) {
            s1 += __shfl_xor(s1, o, 64);
            s2 += __shfl_xor(s2, o, 64);
        }
        float mean = s1 * (1.f / 64.f);
        float var = fmaf(-mean, mean, s2 * (1.f / 64.f));
        if (n < NN)
            out[n * DIM + lane] = (x2 - mean) * rsqrtf(var + LN_EPS) * gg2 + bb2;
    }
}

extern "C" void kernel_launch(void* const* d_in, const int* in_sizes, int n_in,
                              void* d_out, int out_size, void* d_ws, size_t ws_size,
                              hipStream_t stream) {
    const float* feats = (const float*)d_in[0];
    const int*   ei    = (const int*)d_in[1];
    const float* attr  = (const float*)d_in[2];
    const float* Wq = (const float*)d_in[3];
    const float* Wk = (const float*)d_in[4];
    const float* Wv = (const float*)d_in[5];
    const float* Wo = (const float*)d_in[6];
    const float* W1 = (const float*)d_in[7];
    const float* W2 = (const float*)d_in[8];
    const float* bq = (const float*)d_in[9];
    const float* bk = (const float*)d_in[10];
    const float* bv = (const float*)d_in[11];
    const float* bo = (const float*)d_in[12];
    const float* b1 = (const float*)d_in[13];
    const float* b2 = (const float*)d_in[14];
    const float* g1  = (const float*)d_in[15];
    const float* be1 = (const float*)d_in[16];
    const float* g2  = (const float*)d_in[17];
    const float* be2 = (const float*)d_in[18];

    float* out = (float*)d_out;
    float* ws = (float*)d_ws;

    const size_t ND = (size_t)NN * DIM;
    float* q   = ws;                         // NN*64 f32 (pre-scaled 0.25)
    float* agg = ws + ND;                    // NN*64 f32
    unsigned int* kpk = (unsigned int*)(ws + 2 * ND);   // NN*32 u32 (bf16x2)
    unsigned int* vpk = kpk + (size_t)NN * 32;          // NN*32 u32

    int* wi = (int*)(vpk + (size_t)NN * 32);
    int* deg      = wi;                    // NN
    int* cursor   = wi + NN;               // NN   (zeroed together with deg)
    int* tmp      = wi + 2 * NN;           // NN
    int* bsum     = wi + 3 * NN;           // 256
    int* rowptr   = wi + 3 * NN + 256;     // NN+1
    int2* csr     = (int2*)(rowptr + NN + 2); // E packed (8B aligned)

    // ---- CSR build (graph constant across layers) ----
    zero_kernel<<<(2 * NN + 255) / 256, 256, 0, stream>>>(deg, 2 * NN);
    deg_kernel<<<(NEDGE + 255) / 256, 256, 0, stream>>>(ei, deg);
    scan1_kernel<<<SCAN_BLOCKS, 256, 0, stream>>>(deg, tmp, bsum);
    scan2_kernel<<<1, 256, 0, stream>>>(bsum);
    scan3_kernel<<<SCAN_BLOCKS, 256, 0, stream>>>(tmp, bsum, rowptr);
    fill_kernel<<<(NEDGE + 255) / 256, 256, 0, stream>>>(ei, attr, rowptr, cursor, csr);

    const int rowBlocks = (NN + 4 * ROWS - 1) / (4 * ROWS);
    const float* fin = feats;
    for (int l = 0; l < NLAYER; ++l) {
        const size_t wOff = (size_t)l * DIM * DIM;
        const size_t bOff = (size_t)l * DIM;

        qkv_kernel<<<rowBlocks, 256, 0, stream>>>(
            fin, Wq + wOff, Wk + wOff, Wv + wOff,
            bq + bOff, bk + bOff, bv + bOff, q, kpk, vpk);

        attn_kernel<<<NN / 4, 256, 0, stream>>>(rowptr, csr, q, kpk, vpk, agg);

        post_kernel<<<rowBlocks, 256, 0, stream>>>(
            fin, agg,
            Wo + wOff, bo + bOff, W1 + wOff, b1 + bOff, W2 + wOff, b2 + bOff,
            g1 + bOff, be1 + bOff, g2 + bOff, be2 + bOff,
            out + (size_t)l * ND);

        fin = out + (size_t)l * ND;
    }
}